// Round 1
// baseline (1557.700 us; speedup 1.0000x reference)
//
#include <hip/hip_runtime.h>
#include <hip/hip_bf16.h>

// SimpleRetention on MI355X — round 1 (correctness-first baseline).
// Pipeline:
//   K0: QKV projection (fp32 VALU) + xpos rotary, outputs bf16 Q/K/V to ws.
//   K1: streaming "flash retention": per (head, q-tile) accumulate
//       out += (Q K^T * gamma^(q-t) causal) V over key tiles. No score
//       materialization. All tiles staged in LDS (bf16), fp32 accumulate.

#define S_LEN 2048
#define HD 256
#define BN 16

#define TQ 32
#define TK 32
#define QS_STRIDE 264   // bf16 elems; 528 B row stride -> 16B aligned, 2-way banks
#define KS_STRIDE 264
#define SC_STRIDE 36    // fp32 elems; 144 B rows -> 16B aligned

typedef unsigned short ushort_t;

__device__ __forceinline__ void unpack8(uint4 u, float* f) {
  f[0] = __uint_as_float(u.x << 16); f[1] = __uint_as_float(u.x & 0xffff0000u);
  f[2] = __uint_as_float(u.y << 16); f[3] = __uint_as_float(u.y & 0xffff0000u);
  f[4] = __uint_as_float(u.z << 16); f[5] = __uint_as_float(u.z & 0xffff0000u);
  f[6] = __uint_as_float(u.w << 16); f[7] = __uint_as_float(u.w & 0xffff0000u);
}

// ---------------- Kernel 0: QKV projection + xpos ----------------
__global__ __launch_bounds__(256) void qkv_xpos_kernel(
    const float* __restrict__ X, const float* __restrict__ WQ,
    const float* __restrict__ WK, const float* __restrict__ WV,
    __hip_bfloat16* __restrict__ Q, __hip_bfloat16* __restrict__ K,
    __hip_bfloat16* __restrict__ V) {
  __shared__ float xs[16][256];
  const int tid = threadIdx.x;
  const long r0 = (long)blockIdx.x * 16;   // 16 rows of X per block
#pragma unroll
  for (int r = 0; r < 16; ++r) xs[r][tid] = X[(r0 + r) * HD + tid];
  __syncthreads();

  float aq[16], ak[16], av[16];
#pragma unroll
  for (int r = 0; r < 16; ++r) { aq[r] = 0.f; ak[r] = 0.f; av[r] = 0.f; }
  const int j = tid;  // output column
  for (int i = 0; i < 256; i += 4) {
    float4 xv[16];
#pragma unroll
    for (int r = 0; r < 16; ++r) xv[r] = *(const float4*)&xs[r][i];
#pragma unroll
    for (int ii = 0; ii < 4; ++ii) {
      float wq = WQ[(i + ii) * HD + j];
      float wk = WK[(i + ii) * HD + j];
      float wv = WV[(i + ii) * HD + j];
#pragma unroll
      for (int r = 0; r < 16; ++r) {
        float x = ((const float*)&xv[r])[ii];
        aq[r] = fmaf(x, wq, aq[r]);
        ak[r] = fmaf(x, wk, ak[r]);
        av[r] = fmaf(x, wv, av[r]);
      }
    }
  }

  // xpos rotary. pair (2i, 2i+1); thread j handles column j, partner via shfl.
  const int s0 = (int)(r0 & (S_LEN - 1));   // block never spans a head boundary
  const int i2 = j >> 1;                    // frequency index 0..127
  const float inv_freq = exp2f(-(float)i2 * (13.287712379549449f / 128.0f)); // 10000^-(i/128)
  const float base = ((float)(2 * i2) + 102.4f) / 358.4f;
  const float lbase = log2f(base);
  const float sgn = (j & 1) ? 1.0f : -1.0f;
#pragma unroll
  for (int r = 0; r < 16; ++r) {
    float p = (float)(s0 + r);
    float ang = p * inv_freq;
    float sn = sinf(ang), cs = cosf(ang);
    float e = p * (1.0f / 512.0f) * lbase;
    float scl = exp2f(e);    // xpos scale for Q
    float iscl = exp2f(-e);  // downscale for K
    float qv = aq[r], kv = ak[r];
    float qp = __shfl_xor(qv, 1);
    float kp = __shfl_xor(kv, 1);
    // even j: out = x*cos - partner*sin ; odd j: out = x*cos + partner*sin
    float qo = qv * (cs * scl) + sgn * qp * (sn * scl);
    float ko = kv * (cs * iscl) + sgn * kp * (sn * iscl);
    long off = (r0 + r) * HD + j;
    Q[off] = __float2bfloat16(qo);
    K[off] = __float2bfloat16(ko);
    V[off] = __float2bfloat16(av[r]);
  }
}

// ---------------- Kernel 1: streaming retention ----------------
__global__ __launch_bounds__(256) void retention_kernel(
    const ushort_t* __restrict__ Q, const ushort_t* __restrict__ K,
    const ushort_t* __restrict__ V, float* __restrict__ out) {
  __shared__ ushort_t qs[TQ][QS_STRIDE];
  __shared__ ushort_t ks[TK][KS_STRIDE];
  __shared__ ushort_t vs[TK][HD];
  __shared__ float sc[TK][SC_STRIDE];   // scores transposed: sc[t][q]

  const int tid = threadIdx.x;
  const int bn = blockIdx.y;
  const int qt = (int)gridDim.x - 1 - (int)blockIdx.x;  // big tiles first
  const int q0 = qt * TQ;
  const ushort_t* Qh = Q + (long)bn * S_LEN * HD;
  const ushort_t* Kh = K + (long)bn * S_LEN * HD;
  const ushort_t* Vh = V + (long)bn * S_LEN * HD;

#pragma unroll
  for (int r = 0; r < TQ; ++r) qs[r][tid] = Qh[(long)(q0 + r) * HD + tid];

  float acc[4][8];
#pragma unroll
  for (int c = 0; c < 4; ++c)
#pragma unroll
    for (int k = 0; k < 8; ++k) acc[c][k] = 0.f;

  const int qi = tid & 15;   // score rows {qi, qi+16}
  const int ti = tid >> 4;   // score cols {ti, ti+16}  (ti in 0..15)
  const int qg = tid >> 5;   // PV: q group (0..7) -> rows qg*4..+3
  const int hg = tid & 31;   // PV: h cols {hg*4..+3} and {128+hg*4..+3}
  const float LG = -0.045803697f;  // log2(0.96875)

  for (int kt = 0; kt <= qt; ++kt) {
    const int t0 = kt * TK;
#pragma unroll
    for (int r = 0; r < TK; ++r) {
      ks[r][tid] = Kh[(long)(t0 + r) * HD + tid];
      vs[r][tid] = Vh[(long)(t0 + r) * HD + tid];
    }
    __syncthreads();

    // ---- scores: 2q x 2t per thread over 256-deep dot ----
    float s00 = 0.f, s01 = 0.f, s10 = 0.f, s11 = 0.f;
    for (int i = 0; i < 256; i += 8) {
      uint4 ua0 = *(const uint4*)&qs[qi][i];
      uint4 ua1 = *(const uint4*)&qs[qi + 16][i];
      uint4 ub0 = *(const uint4*)&ks[ti][i];
      uint4 ub1 = *(const uint4*)&ks[ti + 16][i];
      float a0f[8], a1f[8], b0f[8], b1f[8];
      unpack8(ua0, a0f); unpack8(ua1, a1f);
      unpack8(ub0, b0f); unpack8(ub1, b1f);
#pragma unroll
      for (int e = 0; e < 8; ++e) {
        s00 = fmaf(a0f[e], b0f[e], s00);
        s01 = fmaf(a0f[e], b1f[e], s01);
        s10 = fmaf(a1f[e], b0f[e], s10);
        s11 = fmaf(a1f[e], b1f[e], s11);
      }
    }
    {
      const int qa = q0 + qi, ta = t0 + ti;
      const int d00 = qa - ta;
      const int d01 = qa - (ta + 16);
      const int d10 = qa + 16 - ta;
      float w00 = (d00 >= 0) ? exp2f((float)d00 * LG) : 0.f;
      float w01 = (d01 >= 0) ? exp2f((float)d01 * LG) : 0.f;
      float w10 = (d10 >= 0) ? exp2f((float)d10 * LG) : 0.f;
      sc[ti][qi]           = s00 * w00;
      sc[ti + 16][qi]      = s01 * w01;
      sc[ti][qi + 16]      = s10 * w10;
      sc[ti + 16][qi + 16] = s11 * w00;  // (qa+16)-(ta+16) == d00
    }
    __syncthreads();

    // ---- PV: acc[4q][8h] += sc[t][q] * V[t][h] ----
#pragma unroll
    for (int t = 0; t < TK; ++t) {
      float4 sv = *(const float4*)&sc[t][qg * 4];
      uint2 v0 = *(const uint2*)&vs[t][hg * 4];
      uint2 v1 = *(const uint2*)&vs[t][128 + hg * 4];
      float vf[8];
      vf[0] = __uint_as_float(v0.x << 16); vf[1] = __uint_as_float(v0.x & 0xffff0000u);
      vf[2] = __uint_as_float(v0.y << 16); vf[3] = __uint_as_float(v0.y & 0xffff0000u);
      vf[4] = __uint_as_float(v1.x << 16); vf[5] = __uint_as_float(v1.x & 0xffff0000u);
      vf[6] = __uint_as_float(v1.y << 16); vf[7] = __uint_as_float(v1.y & 0xffff0000u);
      float svf[4] = {sv.x, sv.y, sv.z, sv.w};
#pragma unroll
      for (int c = 0; c < 4; ++c)
#pragma unroll
        for (int k = 0; k < 8; ++k)
          acc[c][k] = fmaf(svf[c], vf[k], acc[c][k]);
    }
    __syncthreads();
  }

  // epilogue: coalesced float4 stores
  const int h0 = hg * 4;
#pragma unroll
  for (int c = 0; c < 4; ++c) {
    long row = (long)bn * S_LEN + q0 + qg * 4 + c;
    float4 o0 = make_float4(acc[c][0], acc[c][1], acc[c][2], acc[c][3]);
    float4 o1 = make_float4(acc[c][4], acc[c][5], acc[c][6], acc[c][7]);
    *(float4*)&out[row * HD + h0] = o0;
    *(float4*)&out[row * HD + 128 + h0] = o1;
  }
}

extern "C" void kernel_launch(void* const* d_in, const int* in_sizes, int n_in,
                              void* d_out, int out_size, void* d_ws, size_t ws_size,
                              hipStream_t stream) {
  const float* X  = (const float*)d_in[0];
  const float* WQ = (const float*)d_in[1];
  const float* WK = (const float*)d_in[2];
  const float* WV = (const float*)d_in[3];
  float* out = (float*)d_out;

  // workspace: bf16 Q,K,V each (BN, S, HD) = 16.78M elems = 33.5MB*0.5 each
  __hip_bfloat16* Qb = (__hip_bfloat16*)d_ws;
  __hip_bfloat16* Kb = Qb + (size_t)BN * S_LEN * HD;
  __hip_bfloat16* Vb = Kb + (size_t)BN * S_LEN * HD;

  qkv_xpos_kernel<<<dim3((BN * S_LEN) / 16), dim3(256), 0, stream>>>(
      X, WQ, WK, WV, Qb, Kb, Vb);
  retention_kernel<<<dim3(S_LEN / TQ, BN), dim3(256), 0, stream>>>(
      (const ushort_t*)Qb, (const ushort_t*)Kb, (const ushort_t*)Vb, out);
}

// Round 2
// 424.168 us; speedup vs baseline: 3.6724x; 3.6724x over previous
//
#include <hip/hip_runtime.h>
#include <hip/hip_bf16.h>

// SimpleRetention on MI355X — round 2: MFMA retention kernel.
//   K0: QKV projection (fp32 VALU) + xpos rotary -> f16 Q, K, and V^T [bn][h][s].
//   K1: flash-retention with mfma_f32_16x16x32_f16:
//       per (head, 64-q tile): stream 32-key tiles; QK^T via MFMA (Q frags
//       register-resident), decay applied in C-layout, S -> f16 -> LDS
//       round-trip into A-layout (m120 pattern), PV via MFMA, fp32 out.

#define S_LEN 2048
#define HD 256
#define BN 16
#define TQ 64
#define TK 32

#define KS_STRIDE 264   // f16 elems; 528 B rows (33*16B): 16B-aligned, 2-way banks
#define VT_STRIDE 40    // f16 elems; 80 B rows (5*16B)
#define SC_STRIDE 40

typedef _Float16 half8 __attribute__((ext_vector_type(8)));
typedef float floatx4 __attribute__((ext_vector_type(4)));

// ---------------- Kernel 0: QKV projection + xpos (f16 out) ----------------
__global__ __launch_bounds__(256) void qkv_xpos_kernel(
    const float* __restrict__ X, const float* __restrict__ WQ,
    const float* __restrict__ WK, const float* __restrict__ WV,
    _Float16* __restrict__ Q, _Float16* __restrict__ K,
    _Float16* __restrict__ VT) {
  __shared__ float xs[16][256];
  const int tid = threadIdx.x;
  const long r0 = (long)blockIdx.x * 16;   // 16 rows of X per block
#pragma unroll
  for (int r = 0; r < 16; ++r) xs[r][tid] = X[(r0 + r) * HD + tid];
  __syncthreads();

  float aq[16], ak[16], av[16];
#pragma unroll
  for (int r = 0; r < 16; ++r) { aq[r] = 0.f; ak[r] = 0.f; av[r] = 0.f; }
  const int j = tid;  // output column
  for (int i = 0; i < 256; i += 4) {
    float4 xv[16];
#pragma unroll
    for (int r = 0; r < 16; ++r) xv[r] = *(const float4*)&xs[r][i];
#pragma unroll
    for (int ii = 0; ii < 4; ++ii) {
      float wq = WQ[(i + ii) * HD + j];
      float wk = WK[(i + ii) * HD + j];
      float wv = WV[(i + ii) * HD + j];
#pragma unroll
      for (int r = 0; r < 16; ++r) {
        float x = ((const float*)&xv[r])[ii];
        aq[r] = fmaf(x, wq, aq[r]);
        ak[r] = fmaf(x, wk, ak[r]);
        av[r] = fmaf(x, wv, av[r]);
      }
    }
  }

  // xpos rotary. pair (2i, 2i+1); thread j handles column j, partner via shfl.
  const int s0 = (int)(r0 & (S_LEN - 1));   // block never spans a head boundary
  const int bn = (int)(r0 >> 11);
  const int i2 = j >> 1;                    // frequency index 0..127
  const float inv_freq = exp2f(-(float)i2 * (13.287712379549449f / 128.0f)); // 10000^-(i/128)
  const float base = ((float)(2 * i2) + 102.4f) / 358.4f;
  const float lbase = log2f(base);
  const float sgn = (j & 1) ? 1.0f : -1.0f;
  half8 vpack[2];
#pragma unroll
  for (int r = 0; r < 16; ++r) {
    float p = (float)(s0 + r);
    float ang = p * inv_freq;
    float sn = sinf(ang), cs = cosf(ang);
    float e = p * (1.0f / 512.0f) * lbase;
    float scl = exp2f(e);    // xpos scale for Q
    float iscl = exp2f(-e);  // downscale for K
    float qv = aq[r], kv = ak[r];
    float qp = __shfl_xor(qv, 1);
    float kp = __shfl_xor(kv, 1);
    // even j: out = x*cos - partner*sin ; odd j: out = x*cos + partner*sin
    float qo = qv * (cs * scl) + sgn * qp * (sn * scl);
    float ko = kv * (cs * iscl) + sgn * kp * (sn * iscl);
    long off = (r0 + r) * HD + j;
    Q[off] = (_Float16)qo;
    K[off] = (_Float16)ko;
    vpack[r >> 3][r & 7] = (_Float16)av[r];
  }
  // V^T: thread j already holds column j = row h of V^T. 32B contiguous store.
  long vtoff = ((long)bn * HD + j) * S_LEN + s0;
  *(uint4*)&VT[vtoff] = ((const uint4*)vpack)[0];
  *(uint4*)&VT[vtoff + 8] = ((const uint4*)vpack)[1];
}

// ---------------- Kernel 1: MFMA flash retention ----------------
__global__ __launch_bounds__(256) void retention_kernel(
    const _Float16* __restrict__ Q, const _Float16* __restrict__ K,
    const _Float16* __restrict__ VT, float* __restrict__ out) {
  __shared__ _Float16 ks[TK][KS_STRIDE];        // K tile, row-major [t][k]
  __shared__ _Float16 vsT[HD][VT_STRIDE];       // V^T tile [h][t]
  __shared__ _Float16 sc[4][16][SC_STRIDE];     // per-wave S tile [q][t], f16

  const int tid = threadIdx.x;
  const int lane = tid & 63;
  const int w = tid >> 6;            // wave 0..3, owns q rows w*16..+16
  const int l15 = lane & 15;
  const int quad = lane >> 4;

  const int bn = blockIdx.y;
  const int qt = (int)gridDim.x - 1 - (int)blockIdx.x;  // big tiles first
  const int q0 = qt * TQ;

  const _Float16* Qh = Q + (long)bn * S_LEN * HD;
  const _Float16* Kh = K + (long)bn * S_LEN * HD;
  const _Float16* VTh = VT + (long)bn * S_LEN * HD;     // [h][s]

  // Q fragments register-resident: A[m=l15][k=quad*8+j], 8 k-blocks of 32
  half8 qf[8];
  {
    const _Float16* qrow = Qh + (long)(q0 + w * 16 + l15) * HD + quad * 8;
#pragma unroll
    for (int kb = 0; kb < 8; ++kb) qf[kb] = *(const half8*)(qrow + kb * 32);
  }

  floatx4 acc[16];
#pragma unroll
  for (int nt = 0; nt < 16; ++nt) acc[nt] = (floatx4){0.f, 0.f, 0.f, 0.f};

  const float LG = -0.045803697f;  // log2(0.96875)
  const int niter = 2 * qt + 2;    // 32-wide key tiles covering t <= q0+63

  for (int kt = 0; kt < niter; ++kt) {
    const int t0 = kt * TK;
    // ---- stage K tile: 32 rows x 256 f16 (coalesced 64B/thread) ----
    {
      const int row = tid >> 3, col = (tid & 7) * 32;
      const uint4* src = (const uint4*)(Kh + (long)(t0 + row) * HD + col);
      uint4* dst = (uint4*)&ks[row][col];
#pragma unroll
      for (int u = 0; u < 4; ++u) dst[u] = src[u];
    }
    // ---- stage V^T tile: 256 rows x 32 f16 (64B/thread from [h][s]) ----
    {
      const uint4* src = (const uint4*)(VTh + (long)tid * S_LEN + t0);
#pragma unroll
      for (int u = 0; u < 4; ++u) *(uint4*)&vsT[tid][u * 8] = src[u];
    }
    __syncthreads();

    // ---- QK^T: S[16q][32t] per wave = 2 n-tiles x 8 k-steps ----
    floatx4 s0v = (floatx4){0.f, 0.f, 0.f, 0.f};
    floatx4 s1v = (floatx4){0.f, 0.f, 0.f, 0.f};
#pragma unroll
    for (int kb = 0; kb < 8; ++kb) {
      half8 b0 = *(const half8*)&ks[l15][kb * 32 + quad * 8];
      half8 b1 = *(const half8*)&ks[16 + l15][kb * 32 + quad * 8];
      s0v = __builtin_amdgcn_mfma_f32_16x16x32_f16(qf[kb], b0, s0v, 0, 0, 0);
      s1v = __builtin_amdgcn_mfma_f32_16x16x32_f16(qf[kb], b1, s1v, 0, 0, 0);
    }

    // ---- decay in C-layout, convert f16, write to per-wave sc[q][t] ----
    {
      const int qa = q0 + w * 16 + quad * 4;  // + r
#pragma unroll
      for (int r = 0; r < 4; ++r) {
        int d0 = (qa + r) - (t0 + l15);
        int d1 = d0 - 16;
        float w0 = (d0 >= 0) ? exp2f((float)d0 * LG) : 0.f;
        float w1 = (d1 >= 0) ? exp2f((float)d1 * LG) : 0.f;
        sc[w][quad * 4 + r][l15]      = (_Float16)(s0v[r] * w0);
        sc[w][quad * 4 + r][16 + l15] = (_Float16)(s1v[r] * w1);
      }
    }
    __syncthreads();

    // ---- PV: acc[q][h] += S[q][t] V[t][h]; A from sc, B from vsT ----
    half8 af = *(const half8*)&sc[w][l15][quad * 8];
#pragma unroll
    for (int nt = 0; nt < 16; ++nt) {
      half8 bf = *(const half8*)&vsT[nt * 16 + l15][quad * 8];
      acc[nt] = __builtin_amdgcn_mfma_f32_16x16x32_f16(af, bf, acc[nt], 0, 0, 0);
    }
    __syncthreads();
  }

  // ---- epilogue: C-layout scatter, fp32 ----
  const long orow = (long)bn * S_LEN + q0 + w * 16 + quad * 4;
#pragma unroll
  for (int nt = 0; nt < 16; ++nt) {
#pragma unroll
    for (int r = 0; r < 4; ++r) {
      out[(orow + r) * HD + nt * 16 + l15] = acc[nt][r];
    }
  }
}

extern "C" void kernel_launch(void* const* d_in, const int* in_sizes, int n_in,
                              void* d_out, int out_size, void* d_ws, size_t ws_size,
                              hipStream_t stream) {
  const float* X  = (const float*)d_in[0];
  const float* WQ = (const float*)d_in[1];
  const float* WK = (const float*)d_in[2];
  const float* WV = (const float*)d_in[3];
  float* out = (float*)d_out;

  // workspace: f16 Q, K, VT each (BN*S*HD) elems = 16.78 MB -> 50.3 MB total
  _Float16* Qh = (_Float16*)d_ws;
  _Float16* Kh = Qh + (size_t)BN * S_LEN * HD;
  _Float16* VTh = Kh + (size_t)BN * S_LEN * HD;

  qkv_xpos_kernel<<<dim3((BN * S_LEN) / 16), dim3(256), 0, stream>>>(
      X, WQ, WK, WV, Qh, Kh, VTh);
  retention_kernel<<<dim3(S_LEN / TQ, BN), dim3(256), 0, stream>>>(
      Qh, Kh, VTh, out);
}

// Round 3
// 373.642 us; speedup vs baseline: 4.1690x; 1.1352x over previous
//
#include <hip/hip_runtime.h>
#include <hip/hip_bf16.h>

// SimpleRetention on MI355X — round 3: MFMA QKV projection.
//   Kp: transpose W_{Q,K,V} fp32 -> f16 WT[3][n][k] (B-operand layout).
//   K0: gemm_qkv — X@W via mfma_f32_16x16x32_f16, k streamed in 64-chunks
//       through LDS; epilogue applies xpos (Q: scale, K: downscale) in
//       C-layout via shfl_xor(1) col-pairing; V transposed through LDS to
//       VT[bn][h][s] for K1's B-fragment reads.
//   K1: flash-retention (unchanged from round 2).

#define S_LEN 2048
#define HD 256
#define BN 16
#define TQ 64
#define TK 32

#define KS_STRIDE 264   // f16 elems; 528 B rows: 16B-aligned, 2-way banks
#define VT_STRIDE 40
#define SC_STRIDE 40

typedef _Float16 half8 __attribute__((ext_vector_type(8)));
typedef _Float16 half4 __attribute__((ext_vector_type(4)));
typedef float floatx4 __attribute__((ext_vector_type(4)));

// ---------------- Kernel P: W transpose fp32 -> f16 [w][n][k] ----------------
__global__ __launch_bounds__(256) void wprep_kernel(
    const float* __restrict__ WQ, const float* __restrict__ WK,
    const float* __restrict__ WV, _Float16* __restrict__ WT) {
  __shared__ _Float16 trans[64][72];
  const int tid = threadIdx.x;
  const int w = blockIdx.y;
  const int tk = (blockIdx.x & 3) * 64;
  const int tn = (blockIdx.x >> 2) * 64;
  const float* W = (w == 0) ? WQ : (w == 1) ? WK : WV;
  // stage 64k x 64n tile, transposing into trans[n][k]
#pragma unroll
  for (int u = 0; u < 4; ++u) {
    int idx = u * 256 + tid;
    int k = idx >> 4;            // 0..63
    int nq = (idx & 15) * 4;     // 0..60
    float4 v = *(const float4*)&W[(tk + k) * HD + tn + nq];
    trans[nq + 0][k] = (_Float16)v.x;
    trans[nq + 1][k] = (_Float16)v.y;
    trans[nq + 2][k] = (_Float16)v.z;
    trans[nq + 3][k] = (_Float16)v.w;
  }
  __syncthreads();
#pragma unroll
  for (int u = 0; u < 2; ++u) {
    int idx = u * 256 + tid;
    int n = idx >> 3;            // 0..63
    int kq = (idx & 7) * 8;      // 0..56
    *(uint4*)&WT[((long)w * HD + tn + n) * HD + tk + kq] = *(const uint4*)&trans[n][kq];
  }
}

// ---------------- Kernel 0: MFMA QKV projection + xpos ----------------
__global__ __launch_bounds__(256) void gemm_qkv_kernel(
    const float* __restrict__ X, const _Float16* __restrict__ WT,
    _Float16* __restrict__ Q, _Float16* __restrict__ K,
    _Float16* __restrict__ VT) {
  __shared__ __align__(16) unsigned char smem[46080];
  _Float16 (*xs)[72]  = (_Float16(*)[72])smem;            // [64 m][72]
  _Float16 (*wsT)[72] = (_Float16(*)[72])(smem + 9216);   // [256 n][72]

  const int tid = threadIdx.x;
  const int lane = tid & 63;
  const int w = tid >> 6;          // wave 0..3 -> rows w*16..+15
  const int l15 = lane & 15;
  const int quad = lane >> 4;
  const int m0 = blockIdx.x * 64;  // 64 rows, never spans a head (2048%64==0)
  const int wsel = blockIdx.y;     // 0=Q, 1=K, 2=V

  const _Float16* WTw = WT + (long)wsel * HD * HD;

  floatx4 acc[16];
#pragma unroll
  for (int nt = 0; nt < 16; ++nt) acc[nt] = (floatx4){0.f, 0.f, 0.f, 0.f};

  for (int kc = 0; kc < 4; ++kc) {
    const int k0 = kc * 64;
    // stage X chunk 64m x 64k (fp32 -> f16)
#pragma unroll
    for (int u = 0; u < 4; ++u) {
      int idx = u * 256 + tid;
      int m = idx >> 4;            // 0..63
      int kq = (idx & 15) * 4;     // 0..60
      float4 v = *(const float4*)&X[(long)(m0 + m) * HD + k0 + kq];
      half4 h; h[0] = (_Float16)v.x; h[1] = (_Float16)v.y;
      h[2] = (_Float16)v.z; h[3] = (_Float16)v.w;
      *(half4*)&xs[m][kq] = h;
    }
    // stage W^T chunk 256n x 64k (f16 straight copy)
#pragma unroll
    for (int u = 0; u < 8; ++u) {
      int idx = u * 256 + tid;
      int n = idx >> 3;            // 0..255
      int kq = (idx & 7) * 8;      // 0..56
      *(uint4*)&wsT[n][kq] = *(const uint4*)&WTw[(long)n * HD + k0 + kq];
    }
    __syncthreads();

#pragma unroll
    for (int ks2 = 0; ks2 < 2; ++ks2) {
      half8 af = *(const half8*)&xs[w * 16 + l15][ks2 * 32 + quad * 8];
#pragma unroll
      for (int nt = 0; nt < 16; ++nt) {
        half8 bf = *(const half8*)&wsT[nt * 16 + l15][ks2 * 32 + quad * 8];
        acc[nt] = __builtin_amdgcn_mfma_f32_16x16x32_f16(af, bf, acc[nt], 0, 0, 0);
      }
    }
    __syncthreads();
  }

  const int bn = m0 >> 11;
  const int sbase = (m0 & (S_LEN - 1)) + w * 16 + quad * 4;

  if (wsel < 2) {
    // xpos rotary in C-layout: col = nt*16+l15, partner col = lane^1
    _Float16* out = (wsel == 0) ? Q : K;
    const float esgn = (wsel == 0) ? 1.0f : -1.0f;  // Q upscale, K downscale
#pragma unroll
    for (int nt = 0; nt < 16; ++nt) {
      const int col = nt * 16 + l15;
      const int i2 = col >> 1;
      const float sgn = (col & 1) ? 1.0f : -1.0f;
      const float inv_freq = exp2f(-(float)i2 * (13.287712379549449f / 128.0f));
      const float lbase = log2f(((float)(2 * i2) + 102.4f) / 358.4f);
#pragma unroll
      for (int r = 0; r < 4; ++r) {
        float p = (float)(sbase + r);
        float sn = sinf(p * inv_freq), cs = cosf(p * inv_freq);
        float scl = exp2f(esgn * p * (1.0f / 512.0f) * lbase);
        float x = acc[nt][r];
        float xp = __shfl_xor(x, 1);
        float o = x * (cs * scl) + sgn * xp * (sn * scl);
        out[(long)(m0 + w * 16 + quad * 4 + r) * HD + col] = (_Float16)o;
      }
    }
  } else {
    // V: transpose through LDS -> VT[bn][h][s]
    _Float16 (*vt)[72] = (_Float16(*)[72])smem;  // [256 h][72], aliases xs/wsT
#pragma unroll
    for (int nt = 0; nt < 16; ++nt) {
      half4 h; h[0] = (_Float16)acc[nt][0]; h[1] = (_Float16)acc[nt][1];
      h[2] = (_Float16)acc[nt][2]; h[3] = (_Float16)acc[nt][3];
      *(half4*)&vt[nt * 16 + l15][w * 16 + quad * 4] = h;
    }
    __syncthreads();
    const int sblk = m0 & (S_LEN - 1);
#pragma unroll
    for (int u = 0; u < 8; ++u) {
      int idx = u * 256 + tid;
      int h = idx >> 3;            // 0..255
      int sj = (idx & 7) * 8;      // 0..56
      *(uint4*)&VT[((long)bn * HD + h) * S_LEN + sblk + sj] = *(const uint4*)&vt[h][sj];
    }
  }
}

// ---------------- Kernel 1: MFMA flash retention (unchanged) ----------------
__global__ __launch_bounds__(256) void retention_kernel(
    const _Float16* __restrict__ Q, const _Float16* __restrict__ K,
    const _Float16* __restrict__ VT, float* __restrict__ out) {
  __shared__ _Float16 ks[TK][KS_STRIDE];        // K tile, row-major [t][k]
  __shared__ _Float16 vsT[HD][VT_STRIDE];       // V^T tile [h][t]
  __shared__ _Float16 sc[4][16][SC_STRIDE];     // per-wave S tile [q][t], f16

  const int tid = threadIdx.x;
  const int lane = tid & 63;
  const int w = tid >> 6;            // wave 0..3, owns q rows w*16..+16
  const int l15 = lane & 15;
  const int quad = lane >> 4;

  const int bn = blockIdx.y;
  const int qt = (int)gridDim.x - 1 - (int)blockIdx.x;  // big tiles first
  const int q0 = qt * TQ;

  const _Float16* Qh = Q + (long)bn * S_LEN * HD;
  const _Float16* Kh = K + (long)bn * S_LEN * HD;
  const _Float16* VTh = VT + (long)bn * S_LEN * HD;     // [h][s]

  // Q fragments register-resident: A[m=l15][k=quad*8+j], 8 k-blocks of 32
  half8 qf[8];
  {
    const _Float16* qrow = Qh + (long)(q0 + w * 16 + l15) * HD + quad * 8;
#pragma unroll
    for (int kb = 0; kb < 8; ++kb) qf[kb] = *(const half8*)(qrow + kb * 32);
  }

  floatx4 acc[16];
#pragma unroll
  for (int nt = 0; nt < 16; ++nt) acc[nt] = (floatx4){0.f, 0.f, 0.f, 0.f};

  const float LG = -0.045803697f;  // log2(0.96875)
  const int niter = 2 * qt + 2;    // 32-wide key tiles covering t <= q0+63

  for (int kt = 0; kt < niter; ++kt) {
    const int t0 = kt * TK;
    // ---- stage K tile: 32 rows x 256 f16 (coalesced 64B/thread) ----
    {
      const int row = tid >> 3, col = (tid & 7) * 32;
      const uint4* src = (const uint4*)(Kh + (long)(t0 + row) * HD + col);
      uint4* dst = (uint4*)&ks[row][col];
#pragma unroll
      for (int u = 0; u < 4; ++u) dst[u] = src[u];
    }
    // ---- stage V^T tile: 256 rows x 32 f16 (64B/thread from [h][s]) ----
    {
      const uint4* src = (const uint4*)(VTh + (long)tid * S_LEN + t0);
#pragma unroll
      for (int u = 0; u < 4; ++u) *(uint4*)&vsT[tid][u * 8] = src[u];
    }
    __syncthreads();

    // ---- QK^T: S[16q][32t] per wave = 2 n-tiles x 8 k-steps ----
    floatx4 s0v = (floatx4){0.f, 0.f, 0.f, 0.f};
    floatx4 s1v = (floatx4){0.f, 0.f, 0.f, 0.f};
#pragma unroll
    for (int kb = 0; kb < 8; ++kb) {
      half8 b0 = *(const half8*)&ks[l15][kb * 32 + quad * 8];
      half8 b1 = *(const half8*)&ks[16 + l15][kb * 32 + quad * 8];
      s0v = __builtin_amdgcn_mfma_f32_16x16x32_f16(qf[kb], b0, s0v, 0, 0, 0);
      s1v = __builtin_amdgcn_mfma_f32_16x16x32_f16(qf[kb], b1, s1v, 0, 0, 0);
    }

    // ---- decay in C-layout, convert f16, write to per-wave sc[q][t] ----
    {
      const int qa = q0 + w * 16 + quad * 4;  // + r
#pragma unroll
      for (int r = 0; r < 4; ++r) {
        int d0 = (qa + r) - (t0 + l15);
        int d1 = d0 - 16;
        float w0 = (d0 >= 0) ? exp2f((float)d0 * LG) : 0.f;
        float w1 = (d1 >= 0) ? exp2f((float)d1 * LG) : 0.f;
        sc[w][quad * 4 + r][l15]      = (_Float16)(s0v[r] * w0);
        sc[w][quad * 4 + r][16 + l15] = (_Float16)(s1v[r] * w1);
      }
    }
    __syncthreads();

    // ---- PV: acc[q][h] += S[q][t] V[t][h]; A from sc, B from vsT ----
    half8 af = *(const half8*)&sc[w][l15][quad * 8];
#pragma unroll
    for (int nt = 0; nt < 16; ++nt) {
      half8 bf = *(const half8*)&vsT[nt * 16 + l15][quad * 8];
      acc[nt] = __builtin_amdgcn_mfma_f32_16x16x32_f16(af, bf, acc[nt], 0, 0, 0);
    }
    __syncthreads();
  }

  // ---- epilogue: C-layout scatter, fp32 ----
  const long orow = (long)bn * S_LEN + q0 + w * 16 + quad * 4;
#pragma unroll
  for (int nt = 0; nt < 16; ++nt) {
#pragma unroll
    for (int r = 0; r < 4; ++r) {
      out[(orow + r) * HD + nt * 16 + l15] = acc[nt][r];
    }
  }
}

extern "C" void kernel_launch(void* const* d_in, const int* in_sizes, int n_in,
                              void* d_out, int out_size, void* d_ws, size_t ws_size,
                              hipStream_t stream) {
  const float* X  = (const float*)d_in[0];
  const float* WQ = (const float*)d_in[1];
  const float* WK = (const float*)d_in[2];
  const float* WV = (const float*)d_in[3];
  float* out = (float*)d_out;

  // workspace: f16 Q, K, VT each BN*S*HD = 33.55 MB; WT 3*256*256 f16 = 0.39 MB
  _Float16* Qh = (_Float16*)d_ws;
  _Float16* Kh = Qh + (size_t)BN * S_LEN * HD;
  _Float16* VTh = Kh + (size_t)BN * S_LEN * HD;
  _Float16* WT = VTh + (size_t)BN * S_LEN * HD;

  wprep_kernel<<<dim3(16, 3), dim3(256), 0, stream>>>(WQ, WK, WV, WT);
  gemm_qkv_kernel<<<dim3((BN * S_LEN) / 64, 3), dim3(256), 0, stream>>>(
      X, WT, Qh, Kh, VTh);
  retention_kernel<<<dim3(S_LEN / TQ, BN), dim3(256), 0, stream>>>(
      Qh, Kh, VTh, out);
}

// Round 4
// 254.609 us; speedup vs baseline: 6.1180x; 1.4675x over previous
//
#include <hip/hip_runtime.h>
#include <hip/hip_bf16.h>

// SimpleRetention on MI355X — round 4.
// K0: fused QKV gemm — X staged ONCE (f16, XOR-swizzled LDS), 3 wsel in-block,
//     B-frags streamed from L2-resident WT with register double-buffer,
//     mfma_f32_32x32x16_f16; xpos epilogue for Q/K, LDS-transpose for VT.
// K1: retention — TK=64, async global_load_lds staging into swizzled tiles,
//     S^T = K*Q^T operand-swap (b64-packed sc writes), PV 32x32x16, sc aliased
//     into the K-tile (4 barriers/iter), grid swizzled for balance+XCD locality.

#define S_LEN 2048
#define HD 256
#define BN 16

typedef _Float16 half8 __attribute__((ext_vector_type(8)));
typedef _Float16 half4 __attribute__((ext_vector_type(4)));
typedef float floatx16 __attribute__((ext_vector_type(16)));

__device__ __forceinline__ void gl_lds16(const void* g, void* l) {
  __builtin_amdgcn_global_load_lds(
      (const __attribute__((address_space(1))) unsigned int*)(unsigned long long)g,
      (__attribute__((address_space(3))) unsigned int*)(unsigned int)(unsigned long long)l,
      16, 0, 0);
}

// ---------------- Kernel P: W transpose fp32 -> f16 [w][n][k] ----------------
__global__ __launch_bounds__(256) void wprep_kernel(
    const float* __restrict__ WQ, const float* __restrict__ WK,
    const float* __restrict__ WV, _Float16* __restrict__ WT) {
  __shared__ _Float16 trans[64][72];
  const int tid = threadIdx.x;
  const int w = blockIdx.y;
  const int tk = (blockIdx.x & 3) * 64;
  const int tn = (blockIdx.x >> 2) * 64;
  const float* W = (w == 0) ? WQ : (w == 1) ? WK : WV;
#pragma unroll
  for (int u = 0; u < 4; ++u) {
    int idx = u * 256 + tid;
    int k = idx >> 4;
    int nq = (idx & 15) * 4;
    float4 v = *(const float4*)&W[(tk + k) * HD + tn + nq];
    trans[nq + 0][k] = (_Float16)v.x;
    trans[nq + 1][k] = (_Float16)v.y;
    trans[nq + 2][k] = (_Float16)v.z;
    trans[nq + 3][k] = (_Float16)v.w;
  }
  __syncthreads();
#pragma unroll
  for (int u = 0; u < 2; ++u) {
    int idx = u * 256 + tid;
    int n = idx >> 3;
    int kq = (idx & 7) * 8;
    *(uint4*)&WT[((long)w * HD + tn + n) * HD + tk + kq] = *(const uint4*)&trans[n][kq];
  }
}

// ---------------- Kernel 0: fused QKV projection + xpos ----------------
__global__ __launch_bounds__(256) void gemm_qkv_kernel(
    const float* __restrict__ X, const _Float16* __restrict__ WT,
    _Float16* __restrict__ Q, _Float16* __restrict__ K,
    _Float16* __restrict__ VT) {
  __shared__ __align__(16) unsigned char smem[36864];  // xs 32KB swz / vt 36.9KB

  const int tid = threadIdx.x;
  const int lane = tid & 63;
  const int w = tid >> 6;
  const int l31 = lane & 31;
  const int lh = lane >> 5;
  const int m0 = blockIdx.x * 64;
  const int mtile = w & 1;
  const int nhalf = w >> 1;

  // stage X (64 rows x 256 fp32) -> f16 swizzled: chunk p = c ^ (row&31)
#pragma unroll
  for (int i = 0; i < 8; ++i) {
    int id = i * 256 + tid;
    int row = id >> 5, c = id & 31;
    int p = c ^ (row & 31);
    const float4* s = (const float4*)&X[(long)(m0 + row) * HD + c * 8];
    float4 v0 = s[0], v1 = s[1];
    half8 h;
    h[0] = (_Float16)v0.x; h[1] = (_Float16)v0.y;
    h[2] = (_Float16)v0.z; h[3] = (_Float16)v0.w;
    h[4] = (_Float16)v1.x; h[5] = (_Float16)v1.y;
    h[6] = (_Float16)v1.z; h[7] = (_Float16)v1.w;
    *(half8*)(smem + row * 512 + p * 16) = h;
  }
  __syncthreads();

  const int bn = m0 >> 11;
  const int mrow = mtile * 32 + l31;
  const int nbase = nhalf * 128;

  for (int wsel = 0; wsel < 3; ++wsel) {
    const _Float16* Wb = WT + (long)wsel * HD * HD;
    floatx16 acc[4];
#pragma unroll
    for (int nt = 0; nt < 4; ++nt)
#pragma unroll
      for (int e = 0; e < 16; ++e) acc[nt][e] = 0.f;

    half8 bcur[4], bnxt[4];
#pragma unroll
    for (int nt = 0; nt < 4; ++nt)
      bcur[nt] = *(const half8*)(Wb + (long)(nbase + nt * 32 + l31) * HD + lh * 8);
#pragma unroll
    for (int ks16 = 0; ks16 < 16; ++ks16) {
      int p = (ks16 * 2 + lh) ^ l31;
      half8 af = *(const half8*)(smem + mrow * 512 + p * 16);
      if (ks16 < 15) {
#pragma unroll
        for (int nt = 0; nt < 4; ++nt)
          bnxt[nt] = *(const half8*)(Wb + (long)(nbase + nt * 32 + l31) * HD +
                                     (ks16 + 1) * 16 + lh * 8);
      }
#pragma unroll
      for (int nt = 0; nt < 4; ++nt)
        acc[nt] = __builtin_amdgcn_mfma_f32_32x32x16_f16(af, bcur[nt], acc[nt], 0, 0, 0);
#pragma unroll
      for (int nt = 0; nt < 4; ++nt) bcur[nt] = bnxt[nt];
    }

    if (wsel < 2) {
      // xpos in C-layout: col = nbase+nt*32+l31; partner col = lane^1
      _Float16* o = wsel ? K : Q;
      const float esgn = wsel ? -1.0f : 1.0f;  // Q upscale, K downscale
      const int srow0 = (m0 & (S_LEN - 1)) + mtile * 32;
#pragma unroll
      for (int nt = 0; nt < 4; ++nt) {
        int col = nbase + nt * 32 + l31;
        int i2 = col >> 1;
        float inv_freq = exp2f(-(float)i2 * (13.287712379549449f / 128.0f));
        float lbase = log2f(((float)(2 * i2) + 102.4f) / 358.4f);
        float sgn = (col & 1) ? 1.0f : -1.0f;
#pragma unroll
        for (int reg = 0; reg < 16; ++reg) {
          int rmap = (reg & 3) + 8 * (reg >> 2) + 4 * lh;
          float pos = (float)(srow0 + rmap);
          float ang = pos * inv_freq;
          float sn = sinf(ang), cs = cosf(ang);
          float scl = exp2f(esgn * pos * (1.0f / 512.0f) * lbase);
          float x = acc[nt][reg];
          float xp = __shfl_xor(x, 1);
          float ov = x * (cs * scl) + sgn * xp * (sn * scl);
          o[(long)(m0 + mtile * 32 + rmap) * HD + col] = (_Float16)ov;
        }
      }
    } else {
      // V: transpose through LDS -> VT[bn][h][s]
      __syncthreads();  // all waves done reading xs
      _Float16 (*vt)[72] = (_Float16(*)[72])smem;
#pragma unroll
      for (int nt = 0; nt < 4; ++nt) {
        int h = nbase + nt * 32 + l31;
#pragma unroll
        for (int reg = 0; reg < 16; ++reg) {
          int rmap = (reg & 3) + 8 * (reg >> 2) + 4 * lh;
          vt[h][mtile * 32 + rmap] = (_Float16)acc[nt][reg];
        }
      }
      __syncthreads();
      const int sblk = m0 & (S_LEN - 1);
#pragma unroll
      for (int u = 0; u < 8; ++u) {
        int id = u * 256 + tid;
        int h = id >> 3, sj = (id & 7) * 8;
        *(uint4*)&VT[((long)bn * HD + h) * S_LEN + sblk + sj] = *(const uint4*)&vt[h][sj];
      }
    }
  }
}

// ---------------- Kernel 1: retention, TK=64, async swizzled staging ----------
__global__ __launch_bounds__(256) void retention_kernel(
    const _Float16* __restrict__ Q, const _Float16* __restrict__ K,
    const _Float16* __restrict__ VT, float* __restrict__ out) {
  __shared__ __align__(16) unsigned char smem[65536];
  unsigned char* ksb = smem;            // 32KB: 64 t-rows x 512B, p = c ^ (t&31)
  unsigned char* vsb = smem + 32768;    // 32KB: 256 h-rows x 128B, p = c ^ (h&7)
  _Float16 (*sc)[72] = (_Float16(*)[72])smem;  // S^T->S round-trip, aliases ksb

  const int tid = threadIdx.x;
  const int lane = tid & 63;
  const int w = tid >> 6;
  const int l31 = lane & 31;
  const int lh = lane >> 5;
  const int qtile = w >> 1;  // q-half for QK-B / PV-A / output rows
  const int ttile = w & 1;   // t-half for QK-A
  const int hhalf = w & 1;   // h-half for PV-B

  // grid: L%16 = head (same-head -> same XCD mod 8), qt descending (big first)
  const int L = blockIdx.x;
  const int head = L & 15;
  const int qt = 31 - (L >> 4);
  const int q0 = qt * 64;

  const _Float16* Qh = Q + (long)head * S_LEN * HD;
  const _Float16* Kh = K + (long)head * S_LEN * HD;
  const _Float16* VTh = VT + (long)head * HD * S_LEN;

  // Q register-resident as B-frags: n = q-row, k = ks*16 + lh*8 + j
  half8 qf[16];
  {
    const _Float16* qrow = Qh + (long)(q0 + qtile * 32 + l31) * HD + lh * 8;
#pragma unroll
    for (int ks16 = 0; ks16 < 16; ++ks16)
      qf[ks16] = *(const half8*)(qrow + ks16 * 16);
  }

  floatx16 acc[4];
#pragma unroll
  for (int nt = 0; nt < 4; ++nt)
#pragma unroll
    for (int e = 0; e < 16; ++e) acc[nt][e] = 0.f;

  const float LG = -0.0458036896f;  // log2(0.96875)

  for (int kt = 0; kt <= qt; ++kt) {
    const int t0 = kt * 64;
    // async stage K tile (64 x 512B): wave-load li covers rows 2li..2li+1
#pragma unroll
    for (int j = 0; j < 8; ++j) {
      int li = w * 8 + j;
      int row = li * 2 + lh;
      int c = l31 ^ (row & 31);
      gl_lds16(Kh + (long)(t0 + row) * HD + c * 8, ksb + li * 1024);
    }
    // async stage VT tile (256 x 128B): wave-load li covers rows 8li..8li+7
#pragma unroll
    for (int j = 0; j < 8; ++j) {
      int li = w * 8 + j;
      int row = li * 8 + (lane >> 3);
      int c = (lane & 7) ^ (row & 7);
      gl_lds16(VTh + (long)row * S_LEN + t0 + c * 8, vsb + li * 1024);
    }
    __syncthreads();  // B1: staging complete

    // S^T = K * Q^T  (m = t, n = q) -> decay applies in C-layout
    floatx16 s;
#pragma unroll
    for (int e = 0; e < 16; ++e) s[e] = 0.f;
    {
      const unsigned char* kbase = ksb + (ttile * 32 + l31) * 512;
#pragma unroll
      for (int ks16 = 0; ks16 < 16; ++ks16) {
        int p = (ks16 * 2 + lh) ^ l31;
        half8 a = *(const half8*)(kbase + p * 16);
        s = __builtin_amdgcn_mfma_f32_32x32x16_f16(a, qf[ks16], s, 0, 0, 0);
      }
    }
    __syncthreads();  // B2: all ks reads done before sc overwrites ksb

    // decay + causal mask, f16, b64-packed writes into sc[q][t]
    {
      const int qg = q0 + qtile * 32 + l31;
      const int tb = t0 + ttile * 32 + 4 * lh;
#pragma unroll
      for (int g = 0; g < 4; ++g) {
        half4 h4;
#pragma unroll
        for (int r = 0; r < 4; ++r) {
          int d = qg - (tb + 8 * g + r);
          float wv = (d >= 0) ? exp2f((float)d * LG) : 0.f;
          h4[r] = (_Float16)(s[4 * g + r] * wv);
        }
        *(half4*)&sc[qtile * 32 + l31][ttile * 32 + 4 * lh + 8 * g] = h4;
      }
    }
    __syncthreads();  // B3: sc ready

    // PV: acc[q][h] += S[q][t] * V[t][h]
#pragma unroll
    for (int kst = 0; kst < 4; ++kst) {
      half8 a = *(const half8*)&sc[qtile * 32 + l31][kst * 16 + lh * 8];
#pragma unroll
      for (int nt = 0; nt < 4; ++nt) {
        int h = hhalf * 128 + nt * 32 + l31;
        int p = (kst * 2 + lh) ^ (h & 7);
        half8 b = *(const half8*)(vsb + h * 128 + p * 16);
        acc[nt] = __builtin_amdgcn_mfma_f32_32x32x16_f16(a, b, acc[nt], 0, 0, 0);
      }
    }
    __syncthreads();  // B4: sc/vsb reads done before next staging
  }

  // epilogue: C-layout fp32 stores
  const long rbase = (long)head * S_LEN + q0 + qtile * 32;
#pragma unroll
  for (int nt = 0; nt < 4; ++nt) {
    int col = hhalf * 128 + nt * 32 + l31;
#pragma unroll
    for (int reg = 0; reg < 16; ++reg) {
      int rmap = (reg & 3) + 8 * (reg >> 2) + 4 * lh;
      out[(rbase + rmap) * HD + col] = acc[nt][reg];
    }
  }
}

extern "C" void kernel_launch(void* const* d_in, const int* in_sizes, int n_in,
                              void* d_out, int out_size, void* d_ws, size_t ws_size,
                              hipStream_t stream) {
  const float* X  = (const float*)d_in[0];
  const float* WQ = (const float*)d_in[1];
  const float* WK = (const float*)d_in[2];
  const float* WV = (const float*)d_in[3];
  float* out = (float*)d_out;

  _Float16* Qh = (_Float16*)d_ws;
  _Float16* Kh = Qh + (size_t)BN * S_LEN * HD;
  _Float16* VTh = Kh + (size_t)BN * S_LEN * HD;
  _Float16* WT = VTh + (size_t)BN * S_LEN * HD;

  wprep_kernel<<<dim3(16, 3), dim3(256), 0, stream>>>(WQ, WK, WV, WT);
  gemm_qkv_kernel<<<dim3((BN * S_LEN) / 64), dim3(256), 0, stream>>>(
      X, WT, Qh, Kh, VTh);
  retention_kernel<<<dim3(512), dim3(256), 0, stream>>>(Qh, Kh, VTh, out);
}